// Round 10
// baseline (224.584 us; speedup 1.0000x reference)
//
#include <hip/hip_runtime.h>

#define HEADS 4
#define CDIM  64
#define INDIM 128
#define NEG   0.2f
#define CAP     256   // LDS edge slots per wave
#define FASTCAP 252   // fast-path edge limit (leaves pad room to CAP)
#define NGROUP  8     // dst-range groups (~XCDs)
#define BPG     32    // blocks per group

typedef __attribute__((ext_vector_type(8))) short short8;
typedef __attribute__((ext_vector_type(4))) float f32x4;
typedef _Float16 half2_t __attribute__((ext_vector_type(2)));

__device__ __forceinline__ float wave_sum(float v) {
#pragma unroll
    for (int o = 32; o > 0; o >>= 1) v += __shfl_xor(v, o, 64);
    return v;
}
__device__ __forceinline__ int wave_sum_i(int v) {
#pragma unroll
    for (int o = 32; o > 0; o >>= 1) v += __shfl_xor(v, o, 64);
    return v;
}

// f32 -> bf16 bits (RNE) — for the MFMA operand prep only
__device__ __forceinline__ unsigned short f2bf(float f) {
    unsigned u = __float_as_uint(f);
    u = (u + 0x7FFFu + ((u >> 16) & 1u)) >> 16;
    return (unsigned short)u;
}

__device__ __forceinline__ unsigned pk_f16(float a, float b) {
    auto h = __builtin_amdgcn_cvt_pkrtz(a, b);   // __fp16 x2
    return __builtin_bit_cast(unsigned, h);
}
__device__ __forceinline__ half2_t as_h2(unsigned u) {
    return __builtin_bit_cast(half2_t, u);
}

#if __has_builtin(__builtin_amdgcn_fdot2)
__device__ __forceinline__ float fdot2(unsigned a, unsigned b, float c) {
    return __builtin_amdgcn_fdot2(as_h2(a), as_h2(b), c, false);
}
#else
__device__ __forceinline__ float fdot2(unsigned a, unsigned b, float c) {
    half2_t ha = as_h2(a), hb = as_h2(b);
    return c + (float)ha.x * (float)hb.x + (float)ha.y * (float)hb.y;
}
#endif

__device__ __forceinline__ float lrelu(float a) { return a >= 0.f ? a : NEG * a; }

// ---------------- Waug prep (+ deg zeroing): [col][k] bf16, 272 x 128 ----------------
__global__ __launch_bounds__(256) void k_prep(const float* __restrict__ W,
    const float* __restrict__ att_src, const float* __restrict__ att_dst,
    unsigned short* __restrict__ Waug, int* __restrict__ deg, int N)
{
    // fold the deg memset in (saves one launch)
    for (int i = blockIdx.x * 256 + threadIdx.x; i < N; i += 68 * 256) deg[i] = 0;

    const int wv = threadIdx.x >> 6, lane = threadIdx.x & 63;
    const int c = blockIdx.x * 4 + wv;
    if (c >= 272) return;
#pragma unroll
    for (int kk = 0; kk < 2; ++kk) {
        int k = lane + kk * 64;
        float val;
        if (c < 256) {
            val = W[k * 256 + c];
        } else if (c < 260) {
            int q = c - 256; float s = 0.f;
            for (int j = 0; j < 64; ++j) s += W[k * 256 + q * 64 + j] * att_src[q * 64 + j];
            val = s;
        } else if (c < 264) {
            int q = c - 260; float s = 0.f;
            for (int j = 0; j < 64; ++j) s += W[k * 256 + q * 64 + j] * att_dst[q * 64 + j];
            val = s;
        } else {
            val = 0.f;
        }
        Waug[c * 128 + k] = f2bf(val);
    }
}

// ---------------- MFMA projection: h (f16-packed) + logits ----------------
// 512 threads, 8 waves, 128 rows/block -> 2 blocks/CU = 16 waves/CU.
__global__ __launch_bounds__(512) void gemm_mfma(
    const float* __restrict__ x, const unsigned short* __restrict__ Waug,
    uint2* __restrict__ hp, float* __restrict__ a_src, float* __restrict__ a_dst,
    int N)
{
    extern __shared__ char smem[];
    const int t = threadIdx.x;

    const uint4* srcw = (const uint4*)Waug;
    for (int i = t; i < 272 * 16; i += 512) {
        int col = i >> 4, kc = i & 15;
        int off = col * 256 + ((kc * 16) ^ ((col & 7) << 4));
        *(uint4*)(smem + off) = srcw[i];
    }
    __syncthreads();

    const int lane = t & 63, wv = t >> 6;
    const int l = lane & 15, g = lane >> 4;
    const int rowbase = blockIdx.x * 128 + wv * 16;

    int anode = rowbase + l; if (anode >= N) anode = N - 1;
    const float4* xrow = (const float4*)(x + (size_t)anode * INDIM);

    short8 af[4];
#pragma unroll
    for (int ks = 0; ks < 4; ++ks) {
        float4 x0 = xrow[ks * 8 + g * 2];
        float4 x1 = xrow[ks * 8 + g * 2 + 1];
        short8 a;
        a[0] = (short)f2bf(x0.x); a[1] = (short)f2bf(x0.y);
        a[2] = (short)f2bf(x0.z); a[3] = (short)f2bf(x0.w);
        a[4] = (short)f2bf(x1.x); a[5] = (short)f2bf(x1.y);
        a[6] = (short)f2bf(x1.z); a[7] = (short)f2bf(x1.w);
        af[ks] = a;
    }

    f32x4 acc[17];
    const f32x4 zero = {0.f, 0.f, 0.f, 0.f};
#pragma unroll
    for (int tt = 0; tt < 17; ++tt) acc[tt] = zero;

    const int base_b = l * 256;
#pragma unroll
    for (int ks = 0; ks < 4; ++ks) {
        const int koff = (ks * 64 + g * 16) ^ ((l & 7) << 4);
#pragma unroll
        for (int tt = 0; tt < 17; ++tt) {
            short8 bf = *(const short8*)(smem + tt * 4096 + base_b + koff);
            acc[tt] = __builtin_amdgcn_mfma_f32_16x16x32_bf16(af[ks], bf, acc[tt], 0, 0, 0);
        }
    }

#pragma unroll
    for (int j = 0; j < 4; ++j) {
        int node = rowbase + g * 4 + j;
        if (node < N) {
#pragma unroll
            for (int u = 0; u < 4; ++u) {
                int ch = l + 16 * u;
                hp[(size_t)node * CDIM + ch] = make_uint2(
                    pk_f16(acc[u][j],     acc[4 + u][j]),
                    pk_f16(acc[8 + u][j], acc[12 + u][j]));
            }
            if (l < 4)      a_src[node * 4 + l]       = acc[16][j];
            else if (l < 8) a_dst[node * 4 + (l - 4)] = acc[16][j];
        }
    }
}

// ---------------- CSR build (dst-range partitioned) ----------------
// Group g = blockIdx&7 handles only dst in [g*gsz, (g+1)*gsz): all deg/cursor
// atomics and csr writes for a cacheline come from one group (one XCD under
// round-robin dispatch) -> single writeback per line instead of up to 8.
__global__ __launch_bounds__(256) void k_hist(const int* __restrict__ ei,
    int E, int N, int* __restrict__ deg)
{
    const int group = blockIdx.x & (NGROUP - 1);
    const int gblk  = blockIdx.x >> 3;
    const int gsz   = (N + NGROUP - 1) / NGROUP;
    const int lo = group * gsz;
    const int hi = min(N, lo + gsz);
    for (int e = gblk * 256 + threadIdx.x; e < E; e += BPG * 256) {
        int d = ei[E + e];
        if (d >= lo && d < hi) atomicAdd(&deg[d], 1);
    }
}

__global__ __launch_bounds__(256) void k_scan1(const int* __restrict__ deg,
    int* __restrict__ bsum, int N)
{
    const int t = threadIdx.x, lane = t & 63, wv = t >> 6;
    int gid = blockIdx.x * 256 + t;
    int v = (gid < N) ? deg[gid] : 0;
    v = wave_sum_i(v);
    __shared__ int ws[4];
    if (lane == 0) ws[wv] = v;
    __syncthreads();
    if (t == 0) bsum[blockIdx.x] = ws[0] + ws[1] + ws[2] + ws[3];
}

__global__ __launch_bounds__(1024) void k_scan2(int* __restrict__ bsum, int NB)
{
    __shared__ int lds[1024];
    const int t = threadIdx.x;
    int v = (t < NB) ? bsum[t] : 0;
    lds[t] = v;
    __syncthreads();
    for (int o = 1; o < 1024; o <<= 1) {
        int u = (t >= o) ? lds[t - o] : 0;
        __syncthreads();
        lds[t] += u;
        __syncthreads();
    }
    if (t < NB) bsum[t] = lds[t] - v;   // exclusive
}

__global__ __launch_bounds__(256) void k_scan3(const int* __restrict__ deg,
    const int* __restrict__ bsum, int* __restrict__ off, int* __restrict__ cursor,
    int N)
{
    const int t = threadIdx.x, lane = t & 63, wv = t >> 6;
    int gid = blockIdx.x * 256 + t;
    int v = (gid < N) ? deg[gid] : 0;
    int inc = v;
#pragma unroll
    for (int o = 1; o < 64; o <<= 1) {
        int u = __shfl_up(inc, o, 64);
        if (lane >= o) inc += u;
    }
    __shared__ int wtot[4];
    if (lane == 63) wtot[wv] = inc;
    __syncthreads();
    int wpre = 0;
    for (int w = 0; w < wv; ++w) wpre += wtot[w];
    int ex = inc - v + wpre + bsum[blockIdx.x];
    if (gid < N) { off[gid] = ex; cursor[gid] = ex; }
}

__global__ __launch_bounds__(256) void k_scatter(const int* __restrict__ ei,
    int E, int N, int* __restrict__ cursor, int* __restrict__ csr_src)
{
    const int group = blockIdx.x & (NGROUP - 1);
    const int gblk  = blockIdx.x >> 3;
    const int gsz   = (N + NGROUP - 1) / NGROUP;
    const int lo = group * gsz;
    const int hi = min(N, lo + gsz);
    for (int e = gblk * 256 + threadIdx.x; e < E; e += BPG * 256) {
        int d = ei[E + e];
        if (d >= lo && d < hi) {
            int pos = atomicAdd(&cursor[d], 1);
            csr_src[pos] = ei[e];
        }
    }
}

// ---------------- fused aggregation + LayerNorm + PReLU ----------------
__global__ __launch_bounds__(256) void aggr_fused(
    const int* __restrict__ off, const int* __restrict__ deg,
    const int* __restrict__ csr_src,
    const float4* __restrict__ a_src4, const float4* __restrict__ a_dst4,
    const uint2* __restrict__ hp,
    const float* __restrict__ bias, const float* __restrict__ gamma,
    const float* __restrict__ beta, const float* __restrict__ prelu,
    float* __restrict__ out, int N)
{
    __shared__ uint4 slot[4][CAP];
    const int wv   = threadIdx.x >> 6;
    const int lane = threadIdx.x & 63;
    const int wid  = (int)(blockIdx.x * 4u + wv);
    if (wid >= N) return;
    const int d = wid;
    uint4* sl = slot[wv];

    const float4 ad = a_dst4[d];   // wave-uniform
    const int deg_d = deg[d];
    const int beg   = off[d];
    const int nv    = deg_d < FASTCAP ? deg_d : FASTCAP;
    const int nv4   = (nv + 3) & ~3;

    // ---- Phase A: raw exps -> LDS, denom partials ----
    float dl0 = 0.f, dl1 = 0.f, dl2 = 0.f, dl3 = 0.f;
    for (int base = 0; base < deg_d; base += 64) {
        int j = base + lane;
        bool valid = j < deg_d;
        int sv = valid ? csr_src[beg + j] : 0;
        float4 as = a_src4[sv];
        float e0 = valid ? __expf(lrelu(as.x + ad.x)) : 0.f;
        float e1 = valid ? __expf(lrelu(as.y + ad.y)) : 0.f;
        float e2 = valid ? __expf(lrelu(as.z + ad.z)) : 0.f;
        float e3 = valid ? __expf(lrelu(as.w + ad.w)) : 0.f;
        dl0 += e0; dl1 += e1; dl2 += e2; dl3 += e3;
        if (j < CAP) sl[j] = make_uint4(pk_f16(e0, e1), pk_f16(e2, e3), (unsigned)sv, 0u);
    }

    // self-loop exps (wave-uniform)
    float4 asd = a_src4[d];
    float es0 = __expf(lrelu(asd.x + ad.x));
    float es1 = __expf(lrelu(asd.y + ad.y));
    float es2 = __expf(lrelu(asd.z + ad.z));
    float es3 = __expf(lrelu(asd.w + ad.w));

    float r0 = __builtin_amdgcn_rcpf(wave_sum(dl0) + es0);
    float r1 = __builtin_amdgcn_rcpf(wave_sum(dl1) + es1);
    float r2 = __builtin_amdgcn_rcpf(wave_sum(dl2) + es2);
    float r3 = __builtin_amdgcn_rcpf(wave_sum(dl3) + es3);

    // ---- rescale pass: w = e * r (owner lane); pad [nv, nv4) with zeros ----
    for (int base = 0; base < nv4; base += 64) {
        int j = base + lane;
        if (j < nv) {
            uint2 ev = *(const uint2*)&sl[j];
            half2_t e01 = as_h2(ev.x), e23 = as_h2(ev.y);
            *(uint2*)&sl[j] = make_uint2(
                pk_f16((float)e01.x * r0, (float)e01.y * r1),
                pk_f16((float)e23.x * r2, (float)e23.y * r3));
        } else if (j < nv4) {
            sl[j] = make_uint4(0u, 0u, 0u, 0u);   // zero weight, sv=0 -> no-op
        }
    }
    __builtin_amdgcn_wave_barrier();

    // ---- Phase B: accumulate (self-loop init) ----
    uint2 hd = hp[(size_t)d * CDIM + lane];
    unsigned pw01 = pk_f16(es0 * r0, es1 * r1);
    unsigned pw23 = pk_f16(es2 * r2, es3 * r3);
    float acc01 = fdot2(pw01, hd.x, 0.f);
    float acc23 = fdot2(pw23, hd.y, 0.f);

    if (nv4 >= 8) {
        uint4 c0 = sl[0], c1 = sl[1], c2 = sl[2], c3 = sl[3];
        uint2 h0 = hp[(size_t)c0.z * CDIM + lane];
        uint2 h1 = hp[(size_t)c1.z * CDIM + lane];
        uint2 h2 = hp[(size_t)c2.z * CDIM + lane];
        uint2 h3 = hp[(size_t)c3.z * CDIM + lane];
        int j = 0;
        for (; j + 7 < nv4; j += 4) {
            uint4 n0 = sl[j + 4], n1 = sl[j + 5], n2 = sl[j + 6], n3 = sl[j + 7];
            uint2 g0 = hp[(size_t)n0.z * CDIM + lane];
            uint2 g1 = hp[(size_t)n1.z * CDIM + lane];
            uint2 g2 = hp[(size_t)n2.z * CDIM + lane];
            uint2 g3 = hp[(size_t)n3.z * CDIM + lane];
            acc01 = fdot2(c0.x, h0.x, acc01); acc23 = fdot2(c0.y, h0.y, acc23);
            acc01 = fdot2(c1.x, h1.x, acc01); acc23 = fdot2(c1.y, h1.y, acc23);
            acc01 = fdot2(c2.x, h2.x, acc01); acc23 = fdot2(c2.y, h2.y, acc23);
            acc01 = fdot2(c3.x, h3.x, acc01); acc23 = fdot2(c3.y, h3.y, acc23);
            c0 = n0; c1 = n1; c2 = n2; c3 = n3;
            h0 = g0; h1 = g1; h2 = g2; h3 = g3;
        }
        acc01 = fdot2(c0.x, h0.x, acc01); acc23 = fdot2(c0.y, h0.y, acc23);
        acc01 = fdot2(c1.x, h1.x, acc01); acc23 = fdot2(c1.y, h1.y, acc23);
        acc01 = fdot2(c2.x, h2.x, acc01); acc23 = fdot2(c2.y, h2.y, acc23);
        acc01 = fdot2(c3.x, h3.x, acc01); acc23 = fdot2(c3.y, h3.y, acc23);
    } else if (nv4 == 4) {
        uint4 c0 = sl[0], c1 = sl[1], c2 = sl[2], c3 = sl[3];
        uint2 h0 = hp[(size_t)c0.z * CDIM + lane];
        uint2 h1 = hp[(size_t)c1.z * CDIM + lane];
        uint2 h2 = hp[(size_t)c2.z * CDIM + lane];
        uint2 h3 = hp[(size_t)c3.z * CDIM + lane];
        acc01 = fdot2(c0.x, h0.x, acc01); acc23 = fdot2(c0.y, h0.y, acc23);
        acc01 = fdot2(c1.x, h1.x, acc01); acc23 = fdot2(c1.y, h1.y, acc23);
        acc01 = fdot2(c2.x, h2.x, acc01); acc23 = fdot2(c2.y, h2.y, acc23);
        acc01 = fdot2(c3.x, h3.x, acc01); acc23 = fdot2(c3.y, h3.y, acc23);
    }

    // ---- slow path: deg > FASTCAP (recompute with known r) ----
    for (int base = FASTCAP; base < deg_d; base += 64) {
        int jj = base + lane;
        bool valid = jj < deg_d;
        int sv = valid ? csr_src[beg + jj] : 0;
        float4 as = a_src4[sv];
        float e0 = valid ? __expf(lrelu(as.x + ad.x)) : 0.f;
        float e1 = valid ? __expf(lrelu(as.y + ad.y)) : 0.f;
        float e2 = valid ? __expf(lrelu(as.z + ad.z)) : 0.f;
        float e3 = valid ? __expf(lrelu(as.w + ad.w)) : 0.f;
        sl[lane] = make_uint4(pk_f16(e0 * r0, e1 * r1), pk_f16(e2 * r2, e3 * r3),
                              (unsigned)sv, 0u);
        __builtin_amdgcn_wave_barrier();
        int nav = deg_d - base; if (nav > 64) nav = 64;
        for (int q = 0; q < nav; ++q) {
            uint4 t0 = sl[q];
            uint2 h0 = hp[(size_t)t0.z * CDIM + lane];
            acc01 = fdot2(t0.x, h0.x, acc01);
            acc23 = fdot2(t0.y, h0.y, acc23);
        }
        __builtin_amdgcn_wave_barrier();
    }

    // ---- epilogue: mean over heads + bias + LN + PReLU ----
    float v = 0.25f * (acc01 + acc23) + bias[lane];
    float mu  = wave_sum(v) * (1.f / 64.f);
    float df  = v - mu;
    float var = wave_sum(df * df) * (1.f / 64.f);
    float rs  = rsqrtf(var + 1e-5f);
    float o   = df * rs * gamma[lane] + beta[lane];
    float pw  = prelu[0];
    o = o >= 0.f ? o : pw * o;
    out[(size_t)d * CDIM + lane] = o;
}

extern "C" void kernel_launch(void* const* d_in, const int* in_sizes, int n_in,
                              void* d_out, int out_size, void* d_ws, size_t ws_size,
                              hipStream_t stream)
{
    const float* x       = (const float*)d_in[0];
    const int*   ei      = (const int*)  d_in[1];
    const float* W       = (const float*)d_in[2];
    const float* att_src = (const float*)d_in[3];
    const float* att_dst = (const float*)d_in[4];
    const float* bias    = (const float*)d_in[5];
    const float* gamma   = (const float*)d_in[6];
    const float* beta    = (const float*)d_in[7];
    const float* prelu   = (const float*)d_in[8];

    const int N = in_sizes[0] / INDIM;
    const int E = in_sizes[1] / 2;
    float* out = (float*)d_out;
    const int NB = (N + 255) / 256;

    // workspace layout
    uint2* hp     = (uint2*)d_ws;                         // N*64 uint2 (25.6 MB)
    float* a_src  = (float*)(hp + (size_t)N * CDIM);      // N*4 f
    float* a_dst  = a_src + (size_t)N * HEADS;            // N*4 f
    int*   deg    = (int*)(a_dst + (size_t)N * HEADS);    // N
    int*   off    = deg + N;                              // N
    int*   cursor = off + N;                              // N
    int*   bsum   = cursor + N;                           // NB (<=1024)
    int*   csr    = bsum + 1024;                          // E
    unsigned short* Waug = (unsigned short*)(csr + E);    // 272*128 bf16

    k_prep<<<68, 256, 0, stream>>>(W, att_src, att_dst, Waug, deg, N);

    k_hist<<<NGROUP * BPG, 256, 0, stream>>>(ei, E, N, deg);
    k_scan1<<<NB, 256, 0, stream>>>(deg, bsum, N);
    k_scan2<<<1, 1024, 0, stream>>>(bsum, NB);
    k_scan3<<<NB, 256, 0, stream>>>(deg, bsum, off, cursor, N);
    k_scatter<<<NGROUP * BPG, 256, 0, stream>>>(ei, E, N, cursor, csr);

    gemm_mfma<<<(N + 127) / 128, 512, 69632, stream>>>(
        x, Waug, hp, a_src, a_dst, N);

    aggr_fused<<<(N + 3) / 4, 256, 0, stream>>>(
        off, deg, csr, (const float4*)a_src, (const float4*)a_dst, hp,
        bias, gamma, beta, prelu, out, N);
}

// Round 11
// 119.553 us; speedup vs baseline: 1.8785x; 1.8785x over previous
//
#include <hip/hip_runtime.h>

#define HEADS 4
#define CDIM  64
#define INDIM 128
#define NEG   0.2f
#define CAP     256   // LDS edge slots per wave (aggr)
#define FASTCAP 252   // fast-path edge limit
#define NPB     256   // partition blocks for bucket sort

typedef __attribute__((ext_vector_type(8))) short short8;
typedef __attribute__((ext_vector_type(4))) float f32x4;
typedef _Float16 half2_t __attribute__((ext_vector_type(2)));

__device__ __forceinline__ float wave_sum(float v) {
#pragma unroll
    for (int o = 32; o > 0; o >>= 1) v += __shfl_xor(v, o, 64);
    return v;
}
__device__ __forceinline__ int wave_sum_i(int v) {
#pragma unroll
    for (int o = 32; o > 0; o >>= 1) v += __shfl_xor(v, o, 64);
    return v;
}

// f32 -> bf16 bits (RNE) — for the MFMA operand prep only
__device__ __forceinline__ unsigned short f2bf(float f) {
    unsigned u = __float_as_uint(f);
    u = (u + 0x7FFFu + ((u >> 16) & 1u)) >> 16;
    return (unsigned short)u;
}

__device__ __forceinline__ unsigned pk_f16(float a, float b) {
    auto h = __builtin_amdgcn_cvt_pkrtz(a, b);   // __fp16 x2
    return __builtin_bit_cast(unsigned, h);
}
__device__ __forceinline__ half2_t as_h2(unsigned u) {
    return __builtin_bit_cast(half2_t, u);
}

#if __has_builtin(__builtin_amdgcn_fdot2)
__device__ __forceinline__ float fdot2(unsigned a, unsigned b, float c) {
    return __builtin_amdgcn_fdot2(as_h2(a), as_h2(b), c, false);
}
#else
__device__ __forceinline__ float fdot2(unsigned a, unsigned b, float c) {
    half2_t ha = as_h2(a), hb = as_h2(b);
    return c + (float)ha.x * (float)hb.x + (float)ha.y * (float)hb.y;
}
#endif

__device__ __forceinline__ float lrelu(float a) { return a >= 0.f ? a : NEG * a; }

// ---------------- Waug prep: [col][k] bf16, 272 x 128 ----------------
__global__ __launch_bounds__(256) void k_prep(const float* __restrict__ W,
    const float* __restrict__ att_src, const float* __restrict__ att_dst,
    unsigned short* __restrict__ Waug)
{
    const int wv = threadIdx.x >> 6, lane = threadIdx.x & 63;
    const int c = blockIdx.x * 4 + wv;
    if (c >= 272) return;
#pragma unroll
    for (int kk = 0; kk < 2; ++kk) {
        int k = lane + kk * 64;
        float val;
        if (c < 256) {
            val = W[k * 256 + c];
        } else if (c < 260) {
            int q = c - 256; float s = 0.f;
            for (int j = 0; j < 64; ++j) s += W[k * 256 + q * 64 + j] * att_src[q * 64 + j];
            val = s;
        } else if (c < 264) {
            int q = c - 260; float s = 0.f;
            for (int j = 0; j < 64; ++j) s += W[k * 256 + q * 64 + j] * att_dst[q * 64 + j];
            val = s;
        } else {
            val = 0.f;
        }
        Waug[c * 128 + k] = f2bf(val);
    }
}

// ---------------- MFMA projection: h (f16-packed) + logits ----------------
__global__ __launch_bounds__(512) void gemm_mfma(
    const float* __restrict__ x, const unsigned short* __restrict__ Waug,
    uint2* __restrict__ hp, float* __restrict__ a_src, float* __restrict__ a_dst,
    int N)
{
    extern __shared__ char smem[];
    const int t = threadIdx.x;

    const uint4* srcw = (const uint4*)Waug;
    for (int i = t; i < 272 * 16; i += 512) {
        int col = i >> 4, kc = i & 15;
        int off = col * 256 + ((kc * 16) ^ ((col & 7) << 4));
        *(uint4*)(smem + off) = srcw[i];
    }
    __syncthreads();

    const int lane = t & 63, wv = t >> 6;
    const int l = lane & 15, g = lane >> 4;
    const int rowbase = blockIdx.x * 128 + wv * 16;

    int anode = rowbase + l; if (anode >= N) anode = N - 1;
    const float4* xrow = (const float4*)(x + (size_t)anode * INDIM);

    short8 af[4];
#pragma unroll
    for (int ks = 0; ks < 4; ++ks) {
        float4 x0 = xrow[ks * 8 + g * 2];
        float4 x1 = xrow[ks * 8 + g * 2 + 1];
        short8 a;
        a[0] = (short)f2bf(x0.x); a[1] = (short)f2bf(x0.y);
        a[2] = (short)f2bf(x0.z); a[3] = (short)f2bf(x0.w);
        a[4] = (short)f2bf(x1.x); a[5] = (short)f2bf(x1.y);
        a[6] = (short)f2bf(x1.z); a[7] = (short)f2bf(x1.w);
        af[ks] = a;
    }

    f32x4 acc[17];
    const f32x4 zero = {0.f, 0.f, 0.f, 0.f};
#pragma unroll
    for (int tt = 0; tt < 17; ++tt) acc[tt] = zero;

    const int base_b = l * 256;
#pragma unroll
    for (int ks = 0; ks < 4; ++ks) {
        const int koff = (ks * 64 + g * 16) ^ ((l & 7) << 4);
#pragma unroll
        for (int tt = 0; tt < 17; ++tt) {
            short8 bf = *(const short8*)(smem + tt * 4096 + base_b + koff);
            acc[tt] = __builtin_amdgcn_mfma_f32_16x16x32_bf16(af[ks], bf, acc[tt], 0, 0, 0);
        }
    }

#pragma unroll
    for (int j = 0; j < 4; ++j) {
        int node = rowbase + g * 4 + j;
        if (node < N) {
#pragma unroll
            for (int u = 0; u < 4; ++u) {
                int ch = l + 16 * u;
                hp[(size_t)node * CDIM + ch] = make_uint2(
                    pk_f16(acc[u][j],     acc[4 + u][j]),
                    pk_f16(acc[8 + u][j], acc[12 + u][j]));
            }
            if (l < 4)      a_src[node * 4 + l]       = acc[16][j];
            else if (l < 8) a_dst[node * 4 + (l - 4)] = acc[16][j];
        }
    }
}

// ---------------- atomic-free CSR build (two-level bucket sort) ----------------
// bucket = dst >> 8 (256 nodes each). All coordination via LDS (workgroup scope);
// zero device-scope atomics anywhere in the build.

// per-(block,bucket) counts, bucket-major layout counts[bucket*NPB + block]
__global__ __launch_bounds__(256) void k_count(const int* __restrict__ ei,
    int E, int EPB, int NBUK, int* __restrict__ counts)
{
    __shared__ int hist[256];
    const int t = threadIdx.x, blk = blockIdx.x;
    if (t < NBUK) hist[t] = 0;
    __syncthreads();
    const int e0 = blk * EPB;
    for (int j = t; j < EPB; j += 256) {
        int e = e0 + j;
        if (e < E) atomicAdd(&hist[ei[E + e] >> 8], 1);   // LDS atomic
    }
    __syncthreads();
    if (t < NBUK) counts[t * NPB + blk] = hist[t];
}

// generic 3-phase scan over n ints (n = NBUK*256 here)
__global__ __launch_bounds__(256) void k_scan1(const int* __restrict__ arr,
    int* __restrict__ bsum, int n)
{
    const int t = threadIdx.x, lane = t & 63, wv = t >> 6;
    int gid = blockIdx.x * 256 + t;
    int v = (gid < n) ? arr[gid] : 0;
    v = wave_sum_i(v);
    __shared__ int ws[4];
    if (lane == 0) ws[wv] = v;
    __syncthreads();
    if (t == 0) bsum[blockIdx.x] = ws[0] + ws[1] + ws[2] + ws[3];
}

__global__ __launch_bounds__(1024) void k_scan2(int* __restrict__ bsum, int NB)
{
    __shared__ int lds[1024];
    const int t = threadIdx.x;
    int v = (t < NB) ? bsum[t] : 0;
    lds[t] = v;
    __syncthreads();
    for (int o = 1; o < 1024; o <<= 1) {
        int u = (t >= o) ? lds[t - o] : 0;
        __syncthreads();
        lds[t] += u;
        __syncthreads();
    }
    if (t < NB) bsum[t] = lds[t] - v;   // exclusive
}

// in-place exclusive scan finalize
__global__ __launch_bounds__(256) void k_scanip(int* __restrict__ arr,
    const int* __restrict__ bsum, int n)
{
    const int t = threadIdx.x, lane = t & 63, wv = t >> 6;
    int gid = blockIdx.x * 256 + t;
    int v = (gid < n) ? arr[gid] : 0;
    int inc = v;
#pragma unroll
    for (int o = 1; o < 64; o <<= 1) {
        int u = __shfl_up(inc, o, 64);
        if (lane >= o) inc += u;
    }
    __shared__ int wtot[4];
    if (lane == 63) wtot[wv] = inc;
    __syncthreads();
    int wpre = 0;
    for (int w = 0; w < wv; ++w) wpre += wtot[w];
    int ex = inc - v + wpre + bsum[blockIdx.x];
    if (gid < n) arr[gid] = ex;
}

// partition edges into bucket-sorted (src,dst) array; per-(block,bucket)
// ranges are contiguous+disjoint -> coalescing-friendly, no line sharing.
__global__ __launch_bounds__(256) void k_part(const int* __restrict__ ei,
    int E, int EPB, int NBUK, const int* __restrict__ counts,
    uint2* __restrict__ srt)
{
    __shared__ int cb[256];
    const int t = threadIdx.x, blk = blockIdx.x;
    if (t < NBUK) cb[t] = counts[t * NPB + blk];
    __syncthreads();
    const int e0 = blk * EPB;
    for (int j = t; j < EPB; j += 256) {
        int e = e0 + j;
        if (e < E) {
            int s = ei[e], d = ei[E + e];
            int pos = atomicAdd(&cb[d >> 8], 1);   // LDS atomic
            srt[pos] = make_uint2((unsigned)s, (unsigned)d);
        }
    }
}

// per-bucket CSR: one block per bucket (256 nodes). LDS hist + LDS scan ->
// deg/off coalesced; csr scatter confined to the bucket's private region.
__global__ __launch_bounds__(256) void k_bcsr(const uint2* __restrict__ srt,
    const int* __restrict__ counts, int E, int N, int NBUK,
    int* __restrict__ deg, int* __restrict__ off, int* __restrict__ csr)
{
    __shared__ int h[256];
    __shared__ int cur[256];
    __shared__ int wt[4];
    const int t = threadIdx.x, b = blockIdx.x;
    const int bb0 = counts[b * NPB];
    const int bb1 = (b + 1 < NBUK) ? counts[(b + 1) * NPB] : E;
    const int ne = bb1 - bb0;

    h[t] = 0;
    __syncthreads();
    for (int j = t; j < ne; j += 256) atomicAdd(&h[srt[bb0 + j].y & 255], 1);
    __syncthreads();

    int v = h[t];
    const int lane = t & 63, wv = t >> 6;
    int inc = v;
#pragma unroll
    for (int o = 1; o < 64; o <<= 1) {
        int u = __shfl_up(inc, o, 64);
        if (lane >= o) inc += u;
    }
    if (lane == 63) wt[wv] = inc;
    __syncthreads();
    int wpre = 0;
    for (int w = 0; w < wv; ++w) wpre += wt[w];
    int ex = inc - v + wpre;

    int node = (b << 8) + t;
    if (node < N) { deg[node] = v; off[node] = bb0 + ex; }
    cur[t] = bb0 + ex;
    __syncthreads();

    for (int j = t; j < ne; j += 256) {
        uint2 u = srt[bb0 + j];
        int pos = atomicAdd(&cur[u.y & 255], 1);   // LDS atomic
        csr[pos] = (int)u.x;
    }
}

// ---------------- fused aggregation + LayerNorm + PReLU ----------------
__global__ __launch_bounds__(256) void aggr_fused(
    const int* __restrict__ off, const int* __restrict__ deg,
    const int* __restrict__ csr_src,
    const float4* __restrict__ a_src4, const float4* __restrict__ a_dst4,
    const uint2* __restrict__ hp,
    const float* __restrict__ bias, const float* __restrict__ gamma,
    const float* __restrict__ beta, const float* __restrict__ prelu,
    float* __restrict__ out, int N)
{
    __shared__ uint4 slot[4][CAP];
    const int wv   = threadIdx.x >> 6;
    const int lane = threadIdx.x & 63;
    const int wid  = (int)(blockIdx.x * 4u + wv);
    if (wid >= N) return;
    const int d = wid;
    uint4* sl = slot[wv];

    const float4 ad = a_dst4[d];   // wave-uniform
    const int deg_d = deg[d];
    const int beg   = off[d];
    const int nv    = deg_d < FASTCAP ? deg_d : FASTCAP;
    const int nv4   = (nv + 3) & ~3;

    // ---- Phase A: raw exps -> LDS, denom partials ----
    float dl0 = 0.f, dl1 = 0.f, dl2 = 0.f, dl3 = 0.f;
    for (int base = 0; base < deg_d; base += 64) {
        int j = base + lane;
        bool valid = j < deg_d;
        int sv = valid ? csr_src[beg + j] : 0;
        float4 as = a_src4[sv];
        float e0 = valid ? __expf(lrelu(as.x + ad.x)) : 0.f;
        float e1 = valid ? __expf(lrelu(as.y + ad.y)) : 0.f;
        float e2 = valid ? __expf(lrelu(as.z + ad.z)) : 0.f;
        float e3 = valid ? __expf(lrelu(as.w + ad.w)) : 0.f;
        dl0 += e0; dl1 += e1; dl2 += e2; dl3 += e3;
        if (j < CAP) sl[j] = make_uint4(pk_f16(e0, e1), pk_f16(e2, e3), (unsigned)sv, 0u);
    }

    // self-loop exps (wave-uniform)
    float4 asd = a_src4[d];
    float es0 = __expf(lrelu(asd.x + ad.x));
    float es1 = __expf(lrelu(asd.y + ad.y));
    float es2 = __expf(lrelu(asd.z + ad.z));
    float es3 = __expf(lrelu(asd.w + ad.w));

    float r0 = __builtin_amdgcn_rcpf(wave_sum(dl0) + es0);
    float r1 = __builtin_amdgcn_rcpf(wave_sum(dl1) + es1);
    float r2 = __builtin_amdgcn_rcpf(wave_sum(dl2) + es2);
    float r3 = __builtin_amdgcn_rcpf(wave_sum(dl3) + es3);

    // ---- rescale pass: w = e * r (owner lane); pad [nv, nv4) with zeros ----
    for (int base = 0; base < nv4; base += 64) {
        int j = base + lane;
        if (j < nv) {
            uint2 ev = *(const uint2*)&sl[j];
            half2_t e01 = as_h2(ev.x), e23 = as_h2(ev.y);
            *(uint2*)&sl[j] = make_uint2(
                pk_f16((float)e01.x * r0, (float)e01.y * r1),
                pk_f16((float)e23.x * r2, (float)e23.y * r3));
        } else if (j < nv4) {
            sl[j] = make_uint4(0u, 0u, 0u, 0u);   // zero weight, sv=0 -> no-op
        }
    }
    __builtin_amdgcn_wave_barrier();

    // ---- Phase B: accumulate (self-loop init) ----
    uint2 hd = hp[(size_t)d * CDIM + lane];
    unsigned pw01 = pk_f16(es0 * r0, es1 * r1);
    unsigned pw23 = pk_f16(es2 * r2, es3 * r3);
    float acc01 = fdot2(pw01, hd.x, 0.f);
    float acc23 = fdot2(pw23, hd.y, 0.f);

    if (nv4 >= 8) {
        uint4 c0 = sl[0], c1 = sl[1], c2 = sl[2], c3 = sl[3];
        uint2 h0 = hp[(size_t)c0.z * CDIM + lane];
        uint2 h1 = hp[(size_t)c1.z * CDIM + lane];
        uint2 h2 = hp[(size_t)c2.z * CDIM + lane];
        uint2 h3 = hp[(size_t)c3.z * CDIM + lane];
        int j = 0;
        for (; j + 7 < nv4; j += 4) {
            uint4 n0 = sl[j + 4], n1 = sl[j + 5], n2 = sl[j + 6], n3 = sl[j + 7];
            uint2 g0 = hp[(size_t)n0.z * CDIM + lane];
            uint2 g1 = hp[(size_t)n1.z * CDIM + lane];
            uint2 g2 = hp[(size_t)n2.z * CDIM + lane];
            uint2 g3 = hp[(size_t)n3.z * CDIM + lane];
            acc01 = fdot2(c0.x, h0.x, acc01); acc23 = fdot2(c0.y, h0.y, acc23);
            acc01 = fdot2(c1.x, h1.x, acc01); acc23 = fdot2(c1.y, h1.y, acc23);
            acc01 = fdot2(c2.x, h2.x, acc01); acc23 = fdot2(c2.y, h2.y, acc23);
            acc01 = fdot2(c3.x, h3.x, acc01); acc23 = fdot2(c3.y, h3.y, acc23);
            c0 = n0; c1 = n1; c2 = n2; c3 = n3;
            h0 = g0; h1 = g1; h2 = g2; h3 = g3;
        }
        acc01 = fdot2(c0.x, h0.x, acc01); acc23 = fdot2(c0.y, h0.y, acc23);
        acc01 = fdot2(c1.x, h1.x, acc01); acc23 = fdot2(c1.y, h1.y, acc23);
        acc01 = fdot2(c2.x, h2.x, acc01); acc23 = fdot2(c2.y, h2.y, acc23);
        acc01 = fdot2(c3.x, h3.x, acc01); acc23 = fdot2(c3.y, h3.y, acc23);
    } else if (nv4 == 4) {
        uint4 c0 = sl[0], c1 = sl[1], c2 = sl[2], c3 = sl[3];
        uint2 h0 = hp[(size_t)c0.z * CDIM + lane];
        uint2 h1 = hp[(size_t)c1.z * CDIM + lane];
        uint2 h2 = hp[(size_t)c2.z * CDIM + lane];
        uint2 h3 = hp[(size_t)c3.z * CDIM + lane];
        acc01 = fdot2(c0.x, h0.x, acc01); acc23 = fdot2(c0.y, h0.y, acc23);
        acc01 = fdot2(c1.x, h1.x, acc01); acc23 = fdot2(c1.y, h1.y, acc23);
        acc01 = fdot2(c2.x, h2.x, acc01); acc23 = fdot2(c2.y, h2.y, acc23);
        acc01 = fdot2(c3.x, h3.x, acc01); acc23 = fdot2(c3.y, h3.y, acc23);
    }

    // ---- slow path: deg > FASTCAP (recompute with known r) ----
    for (int base = FASTCAP; base < deg_d; base += 64) {
        int jj = base + lane;
        bool valid = jj < deg_d;
        int sv = valid ? csr_src[beg + jj] : 0;
        float4 as = a_src4[sv];
        float e0 = valid ? __expf(lrelu(as.x + ad.x)) : 0.f;
        float e1 = valid ? __expf(lrelu(as.y + ad.y)) : 0.f;
        float e2 = valid ? __expf(lrelu(as.z + ad.z)) : 0.f;
        float e3 = valid ? __expf(lrelu(as.w + ad.w)) : 0.f;
        sl[lane] = make_uint4(pk_f16(e0 * r0, e1 * r1), pk_f16(e2 * r2, e3 * r3),
                              (unsigned)sv, 0u);
        __builtin_amdgcn_wave_barrier();
        int nav = deg_d - base; if (nav > 64) nav = 64;
        for (int q = 0; q < nav; ++q) {
            uint4 t0 = sl[q];
            uint2 h0 = hp[(size_t)t0.z * CDIM + lane];
            acc01 = fdot2(t0.x, h0.x, acc01);
            acc23 = fdot2(t0.y, h0.y, acc23);
        }
        __builtin_amdgcn_wave_barrier();
    }

    // ---- epilogue: mean over heads + bias + LN + PReLU ----
    float v = 0.25f * (acc01 + acc23) + bias[lane];
    float mu  = wave_sum(v) * (1.f / 64.f);
    float df  = v - mu;
    float var = wave_sum(df * df) * (1.f / 64.f);
    float rs  = rsqrtf(var + 1e-5f);
    float o   = df * rs * gamma[lane] + beta[lane];
    float pw  = prelu[0];
    o = o >= 0.f ? o : pw * o;
    out[(size_t)d * CDIM + lane] = o;
}

extern "C" void kernel_launch(void* const* d_in, const int* in_sizes, int n_in,
                              void* d_out, int out_size, void* d_ws, size_t ws_size,
                              hipStream_t stream)
{
    const float* x       = (const float*)d_in[0];
    const int*   ei      = (const int*)  d_in[1];
    const float* W       = (const float*)d_in[2];
    const float* att_src = (const float*)d_in[3];
    const float* att_dst = (const float*)d_in[4];
    const float* bias    = (const float*)d_in[5];
    const float* gamma   = (const float*)d_in[6];
    const float* beta    = (const float*)d_in[7];
    const float* prelu   = (const float*)d_in[8];

    const int N = in_sizes[0] / INDIM;
    const int E = in_sizes[1] / 2;
    float* out = (float*)d_out;

    const int NBUK = (N + 255) >> 8;            // 196 buckets of 256 nodes
    const int EPB  = (E + NPB - 1) / NPB;       // edges per partition block
    const int NCNT = NBUK * NPB;                // counts length (50176)

    // workspace layout
    uint2* hp     = (uint2*)d_ws;                         // N*64 uint2 (25.6 MB)
    float* a_src  = (float*)(hp + (size_t)N * CDIM);      // N*4 f
    float* a_dst  = a_src + (size_t)N * HEADS;            // N*4 f
    int*   deg    = (int*)(a_dst + (size_t)N * HEADS);    // N
    int*   off    = deg + N;                              // N
    int*   counts = off + N;                              // NBUK*256
    int*   bsum   = counts + NCNT;                        // <=1024
    uint2* srt    = (uint2*)(bsum + 1024);                // E uint2 (8B-aligned)
    int*   csr    = (int*)(srt + E);                      // E
    unsigned short* Waug = (unsigned short*)(csr + E);    // 272*128 bf16

    k_prep<<<68, 256, 0, stream>>>(W, att_src, att_dst, Waug);

    // atomic-free CSR build
    k_count<<<NPB, 256, 0, stream>>>(ei, E, EPB, NBUK, counts);
    k_scan1<<<NBUK, 256, 0, stream>>>(counts, bsum, NCNT);
    k_scan2<<<1, 1024, 0, stream>>>(bsum, NBUK);
    k_scanip<<<NBUK, 256, 0, stream>>>(counts, bsum, NCNT);
    k_part<<<NPB, 256, 0, stream>>>(ei, E, EPB, NBUK, counts, srt);
    k_bcsr<<<NBUK, 256, 0, stream>>>(srt, counts, E, N, NBUK, deg, off, csr);

    gemm_mfma<<<(N + 127) / 128, 512, 69632, stream>>>(
        x, Waug, hp, a_src, a_dst, N);

    aggr_fused<<<(N + 3) / 4, 256, 0, stream>>>(
        off, deg, csr, (const float4*)a_src, (const float4*)a_dst, hp,
        bias, gamma, beta, prelu, out, N);
}

// Round 12
// 114.579 us; speedup vs baseline: 1.9601x; 1.0434x over previous
//
#include <hip/hip_runtime.h>

#define HEADS 4
#define CDIM  64
#define INDIM 128
#define NEG   0.2f
#define CAP     256   // LDS edge slots per wave (aggr)
#define FASTCAP 252   // fast-path edge limit
#define NPB     256   // partition blocks for bucket sort

typedef __attribute__((ext_vector_type(8))) short short8;
typedef __attribute__((ext_vector_type(4))) float f32x4;
typedef _Float16 half2_t __attribute__((ext_vector_type(2)));

__device__ __forceinline__ float wave_sum(float v) {
#pragma unroll
    for (int o = 32; o > 0; o >>= 1) v += __shfl_xor(v, o, 64);
    return v;
}
__device__ __forceinline__ int wave_sum_i(int v) {
#pragma unroll
    for (int o = 32; o > 0; o >>= 1) v += __shfl_xor(v, o, 64);
    return v;
}

// f32 -> bf16 bits (RNE) — for the MFMA operand prep only
__device__ __forceinline__ unsigned short f2bf(float f) {
    unsigned u = __float_as_uint(f);
    u = (u + 0x7FFFu + ((u >> 16) & 1u)) >> 16;
    return (unsigned short)u;
}

__device__ __forceinline__ unsigned pk_f16(float a, float b) {
    auto h = __builtin_amdgcn_cvt_pkrtz(a, b);   // __fp16 x2
    return __builtin_bit_cast(unsigned, h);
}
__device__ __forceinline__ half2_t as_h2(unsigned u) {
    return __builtin_bit_cast(half2_t, u);
}

__device__ __forceinline__ float lrelu(float a) { return a >= 0.f ? a : NEG * a; }

// raw-e accumulate: 4 heads, f32 accum from f16 operands (v_fma_mix)
__device__ __forceinline__ void acc_edge(uint4 c, uint2 h,
    float& a0, float& a1, float& a2, float& a3)
{
    half2_t e01 = as_h2(c.x), e23 = as_h2(c.y);
    half2_t h01 = as_h2(h.x), h23 = as_h2(h.y);
    a0 = fmaf((float)e01.x, (float)h01.x, a0);
    a1 = fmaf((float)e01.y, (float)h01.y, a1);
    a2 = fmaf((float)e23.x, (float)h23.x, a2);
    a3 = fmaf((float)e23.y, (float)h23.y, a3);
}

// ---------------- count (bucket hist) + Waug prep, merged ----------------
__global__ __launch_bounds__(256) void k_count_prep(const int* __restrict__ ei,
    int E, int EPB, int NBUK, int* __restrict__ counts,
    const float* __restrict__ W, const float* __restrict__ att_src,
    const float* __restrict__ att_dst, unsigned short* __restrict__ Waug)
{
    __shared__ int hist[256];
    const int t = threadIdx.x, blk = blockIdx.x;
    hist[t] = 0;
    __syncthreads();
    const int e0 = blk * EPB;
    for (int j = t; j < EPB; j += 256) {
        int e = e0 + j;
        if (e < E) atomicAdd(&hist[ei[E + e] >> 8], 1);   // LDS atomic
    }
    __syncthreads();
    if (t < NBUK) counts[t * NPB + blk] = hist[t];

    // Waug prep: one (col,k) entry per global thread
    int idx = blk * 256 + t;
    if (idx < 272 * 128) {
        int c = idx >> 7, k = idx & 127;
        float val;
        if (c < 256) {
            val = W[k * 256 + c];
        } else if (c < 260) {
            int q = c - 256; float s = 0.f;
            for (int j = 0; j < 64; ++j) s += W[k * 256 + q * 64 + j] * att_src[q * 64 + j];
            val = s;
        } else if (c < 264) {
            int q = c - 260; float s = 0.f;
            for (int j = 0; j < 64; ++j) s += W[k * 256 + q * 64 + j] * att_dst[q * 64 + j];
            val = s;
        } else {
            val = 0.f;
        }
        Waug[c * 128 + k] = f2bf(val);
    }
}

// ---------------- scan, phase 1: per-block sums ----------------
__global__ __launch_bounds__(256) void k_scan1(const int* __restrict__ arr,
    int* __restrict__ bsum, int n)
{
    const int t = threadIdx.x, lane = t & 63, wv = t >> 6;
    int gid = blockIdx.x * 256 + t;
    int v = (gid < n) ? arr[gid] : 0;
    v = wave_sum_i(v);
    __shared__ int ws[4];
    if (lane == 0) ws[wv] = v;
    __syncthreads();
    if (t == 0) bsum[blockIdx.x] = ws[0] + ws[1] + ws[2] + ws[3];
}

// ---------------- scan, phase 2: finalize in place (self-computed prefix) ----------------
__global__ __launch_bounds__(256) void k_scanip2(int* __restrict__ arr,
    const int* __restrict__ bsum, int NB, int n)
{
    __shared__ int wred[4];
    __shared__ int wtot[4];
    __shared__ int spre;
    const int t = threadIdx.x, lane = t & 63, wv = t >> 6, b = blockIdx.x;

    // prefix of bsum[0..b) — each block computes its own (one wave-reduce)
    int u0 = (t < NB && t < b) ? bsum[t] : 0;
    u0 = wave_sum_i(u0);
    if (lane == 0) wred[wv] = u0;
    __syncthreads();
    if (t == 0) spre = wred[0] + wred[1] + wred[2] + wred[3];
    __syncthreads();

    int gid = b * 256 + t;
    int v = (gid < n) ? arr[gid] : 0;
    int inc = v;
#pragma unroll
    for (int o = 1; o < 64; o <<= 1) {
        int u = __shfl_up(inc, o, 64);
        if (lane >= o) inc += u;
    }
    if (lane == 63) wtot[wv] = inc;
    __syncthreads();
    int wpre = 0;
    for (int w = 0; w < wv; ++w) wpre += wtot[w];
    int ex = inc - v + wpre + spre;
    if (gid < n) arr[gid] = ex;
}

// ---------------- partition: packed u32 (src<<8 | dst&255) ----------------
__global__ __launch_bounds__(256) void k_part(const int* __restrict__ ei,
    int E, int EPB, int NBUK, const int* __restrict__ counts,
    unsigned* __restrict__ srt)
{
    __shared__ int cb[256];
    const int t = threadIdx.x, blk = blockIdx.x;
    if (t < NBUK) cb[t] = counts[t * NPB + blk];
    __syncthreads();
    const int e0 = blk * EPB;
    for (int j = t; j < EPB; j += 256) {
        int e = e0 + j;
        if (e < E) {
            int s = ei[e], d = ei[E + e];
            int pos = atomicAdd(&cb[d >> 8], 1);   // LDS atomic
            srt[pos] = ((unsigned)s << 8) | ((unsigned)d & 255u);
        }
    }
}

// ---------------- per-bucket CSR ----------------
__global__ __launch_bounds__(256) void k_bcsr(const unsigned* __restrict__ srt,
    const int* __restrict__ counts, int E, int N, int NBUK,
    int* __restrict__ deg, int* __restrict__ off, int* __restrict__ csr)
{
    __shared__ int h[256];
    __shared__ int cur[256];
    __shared__ int wt[4];
    const int t = threadIdx.x, b = blockIdx.x;
    const int bb0 = counts[b * NPB];
    const int bb1 = (b + 1 < NBUK) ? counts[(b + 1) * NPB] : E;
    const int ne = bb1 - bb0;

    h[t] = 0;
    __syncthreads();
    for (int j = t; j < ne; j += 256) atomicAdd(&h[srt[bb0 + j] & 255u], 1);
    __syncthreads();

    int v = h[t];
    const int lane = t & 63, wv = t >> 6;
    int inc = v;
#pragma unroll
    for (int o = 1; o < 64; o <<= 1) {
        int u = __shfl_up(inc, o, 64);
        if (lane >= o) inc += u;
    }
    if (lane == 63) wt[wv] = inc;
    __syncthreads();
    int wpre = 0;
    for (int w = 0; w < wv; ++w) wpre += wt[w];
    int ex = inc - v + wpre;

    int node = (b << 8) + t;
    if (node < N) { deg[node] = v; off[node] = bb0 + ex; }
    cur[t] = bb0 + ex;
    __syncthreads();

    for (int j = t; j < ne; j += 256) {
        unsigned u = srt[bb0 + j];
        int pos = atomicAdd(&cur[u & 255u], 1);   // LDS atomic
        csr[pos] = (int)(u >> 8);
    }
}

// ---------------- MFMA projection: h (f16-packed) + logits ----------------
__global__ __launch_bounds__(512) void gemm_mfma(
    const float* __restrict__ x, const unsigned short* __restrict__ Waug,
    uint2* __restrict__ hp, float* __restrict__ a_src, float* __restrict__ a_dst,
    int N)
{
    extern __shared__ char smem[];
    const int t = threadIdx.x;

    const uint4* srcw = (const uint4*)Waug;
    for (int i = t; i < 272 * 16; i += 512) {
        int col = i >> 4, kc = i & 15;
        int off = col * 256 + ((kc * 16) ^ ((col & 7) << 4));
        *(uint4*)(smem + off) = srcw[i];
    }
    __syncthreads();

    const int lane = t & 63, wv = t >> 6;
    const int l = lane & 15, g = lane >> 4;
    const int rowbase = blockIdx.x * 128 + wv * 16;

    int anode = rowbase + l; if (anode >= N) anode = N - 1;
    const float4* xrow = (const float4*)(x + (size_t)anode * INDIM);

    short8 af[4];
#pragma unroll
    for (int ks = 0; ks < 4; ++ks) {
        float4 x0 = xrow[ks * 8 + g * 2];
        float4 x1 = xrow[ks * 8 + g * 2 + 1];
        short8 a;
        a[0] = (short)f2bf(x0.x); a[1] = (short)f2bf(x0.y);
        a[2] = (short)f2bf(x0.z); a[3] = (short)f2bf(x0.w);
        a[4] = (short)f2bf(x1.x); a[5] = (short)f2bf(x1.y);
        a[6] = (short)f2bf(x1.z); a[7] = (short)f2bf(x1.w);
        af[ks] = a;
    }

    f32x4 acc[17];
    const f32x4 zero = {0.f, 0.f, 0.f, 0.f};
#pragma unroll
    for (int tt = 0; tt < 17; ++tt) acc[tt] = zero;

    const int base_b = l * 256;
#pragma unroll
    for (int ks = 0; ks < 4; ++ks) {
        const int koff = (ks * 64 + g * 16) ^ ((l & 7) << 4);
#pragma unroll
        for (int tt = 0; tt < 17; ++tt) {
            short8 bf = *(const short8*)(smem + tt * 4096 + base_b + koff);
            acc[tt] = __builtin_amdgcn_mfma_f32_16x16x32_bf16(af[ks], bf, acc[tt], 0, 0, 0);
        }
    }

#pragma unroll
    for (int j = 0; j < 4; ++j) {
        int node = rowbase + g * 4 + j;
        if (node < N) {
#pragma unroll
            for (int u = 0; u < 4; ++u) {
                int ch = l + 16 * u;
                hp[(size_t)node * CDIM + ch] = make_uint2(
                    pk_f16(acc[u][j],     acc[4 + u][j]),
                    pk_f16(acc[8 + u][j], acc[12 + u][j]));
            }
            if (l < 4)      a_src[node * 4 + l]       = acc[16][j];
            else if (l < 8) a_dst[node * 4 + (l - 4)] = acc[16][j];
        }
    }
}

// ---------------- fused aggregation + LayerNorm + PReLU ----------------
// Post-normalization: Phase A stores RAW exps (f16) + src in LDS and keeps
// per-lane denom partials; Phase B accumulates raw e*h into 4 f32 accums
// (v_fma_mix). Denominator wave_sums issue AFTER the prologue gathers, so
// the shuffle-chain latency hides under gather latency. Self-loop and the
// 1/den division fold into the epilogue.
__global__ __launch_bounds__(256) void aggr_fused(
    const int* __restrict__ off, const int* __restrict__ deg,
    const int* __restrict__ csr_src,
    const float4* __restrict__ a_src4, const float4* __restrict__ a_dst4,
    const uint2* __restrict__ hp,
    const float* __restrict__ bias, const float* __restrict__ gamma,
    const float* __restrict__ beta, const float* __restrict__ prelu,
    float* __restrict__ out, int N)
{
    __shared__ uint4 slot[4][CAP];
    const int wv   = threadIdx.x >> 6;
    const int lane = threadIdx.x & 63;
    const int wid  = (int)(blockIdx.x * 4u + wv);
    if (wid >= N) return;
    const int d = wid;
    uint4* sl = slot[wv];

    // hoisted epilogue params + self row/logits (independent loads)
    const float bl = bias[lane], gl = gamma[lane], bt = beta[lane], pw = prelu[0];
    const float4 ad  = a_dst4[d];
    const float4 asd = a_src4[d];
    const uint2  hd  = hp[(size_t)d * CDIM + lane];

    const int deg_d = deg[d];
    const int beg   = off[d];
    const int nv    = deg_d < FASTCAP ? deg_d : FASTCAP;
    const int nv4   = (nv + 3) & ~3;

    // ---- Phase A: raw exps -> LDS, denom partials (invalid lanes store 0s = pad) ----
    float dl0 = 0.f, dl1 = 0.f, dl2 = 0.f, dl3 = 0.f;
    for (int base = 0; base < deg_d; base += 64) {
        int j = base + lane;
        bool valid = j < deg_d;
        int sv = valid ? csr_src[beg + j] : 0;
        float4 as = a_src4[sv];
        float e0 = valid ? __expf(lrelu(as.x + ad.x)) : 0.f;
        float e1 = valid ? __expf(lrelu(as.y + ad.y)) : 0.f;
        float e2 = valid ? __expf(lrelu(as.z + ad.z)) : 0.f;
        float e3 = valid ? __expf(lrelu(as.w + ad.w)) : 0.f;
        dl0 += e0; dl1 += e1; dl2 += e2; dl3 += e3;
        if (j < nv4) sl[j] = make_uint4(pk_f16(e0, e1), pk_f16(e2, e3),
                                        valid ? (unsigned)sv : 0u, 0u);
    }
    __builtin_amdgcn_wave_barrier();

    // self-loop raw exps (wave-uniform)
    float es0 = __expf(lrelu(asd.x + ad.x));
    float es1 = __expf(lrelu(asd.y + ad.y));
    float es2 = __expf(lrelu(asd.z + ad.z));
    float es3 = __expf(lrelu(asd.w + ad.w));

    // ---- Phase B prologue: issue first 4 slot reads + gathers ----
    float a0 = 0.f, a1 = 0.f, a2 = 0.f, a3 = 0.f;
    uint4 c0, c1, c2, c3;
    uint2 h0, h1, h2, h3;
    if (nv4 >= 4) {
        c0 = sl[0]; c1 = sl[1]; c2 = sl[2]; c3 = sl[3];
        h0 = hp[(size_t)c0.z * CDIM + lane];
        h1 = hp[(size_t)c1.z * CDIM + lane];
        h2 = hp[(size_t)c2.z * CDIM + lane];
        h3 = hp[(size_t)c3.z * CDIM + lane];
    }

    // ---- denominators: shuffle chains overlap the in-flight gathers ----
    float den0 = wave_sum(dl0) + es0;
    float den1 = wave_sum(dl1) + es1;
    float den2 = wave_sum(dl2) + es2;
    float den3 = wave_sum(dl3) + es3;
    float r0 = __builtin_amdgcn_rcpf(den0);
    float r1 = __builtin_amdgcn_rcpf(den1);
    float r2 = __builtin_amdgcn_rcpf(den2);
    float r3 = __builtin_amdgcn_rcpf(den3);

    // ---- Phase B main loop: register double-buffered ----
    if (nv4 >= 4) {
        int j = 0;
        for (; j + 7 < nv4; j += 4) {
            uint4 n0 = sl[j + 4], n1 = sl[j + 5], n2 = sl[j + 6], n3 = sl[j + 7];
            uint2 g0 = hp[(size_t)n0.z * CDIM + lane];
            uint2 g1 = hp[(size_t)n1.z * CDIM + lane];
            uint2 g2 = hp[(size_t)n2.z * CDIM + lane];
            uint2 g3 = hp[(size_t)n3.z * CDIM + lane];
            acc_edge(c0, h0, a0, a1, a2, a3);
            acc_edge(c1, h1, a0, a1, a2, a3);
            acc_edge(c2, h2, a0, a1, a2, a3);
            acc_edge(c3, h3, a0, a1, a2, a3);
            c0 = n0; c1 = n1; c2 = n2; c3 = n3;
            h0 = g0; h1 = g1; h2 = g2; h3 = g3;
        }
        acc_edge(c0, h0, a0, a1, a2, a3);
        acc_edge(c1, h1, a0, a1, a2, a3);
        acc_edge(c2, h2, a0, a1, a2, a3);
        acc_edge(c3, h3, a0, a1, a2, a3);
    }

    // ---- slow path: deg > FASTCAP (recompute raw exps) ----
    for (int base = FASTCAP; base < deg_d; base += 64) {
        int jj = base + lane;
        bool valid = jj < deg_d;
        int sv = valid ? csr_src[beg + jj] : 0;
        float4 as = a_src4[sv];
        float e0 = valid ? __expf(lrelu(as.x + ad.x)) : 0.f;
        float e1 = valid ? __expf(lrelu(as.y + ad.y)) : 0.f;
        float e2 = valid ? __expf(lrelu(as.z + ad.z)) : 0.f;
        float e3 = valid ? __expf(lrelu(as.w + ad.w)) : 0.f;
        sl[lane] = make_uint4(pk_f16(e0, e1), pk_f16(e2, e3),
                              valid ? (unsigned)sv : 0u, 0u);
        __builtin_amdgcn_wave_barrier();
        int nav = deg_d - base; if (nav > 64) nav = 64;
        for (int q = 0; q < nav; ++q) {
            uint4 t0 = sl[q];
            uint2 hq = hp[(size_t)t0.z * CDIM + lane];
            acc_edge(t0, hq, a0, a1, a2, a3);
        }
        __builtin_amdgcn_wave_barrier();
    }

    // ---- epilogue: self-loop + normalize + mean + bias + LN + PReLU ----
    half2_t hd01 = as_h2(hd.x), hd23 = as_h2(hd.y);
    a0 = fmaf(es0, (float)hd01.x, a0);
    a1 = fmaf(es1, (float)hd01.y, a1);
    a2 = fmaf(es2, (float)hd23.x, a2);
    a3 = fmaf(es3, (float)hd23.y, a3);

    float v = 0.25f * (a0 * r0 + a1 * r1 + a2 * r2 + a3 * r3) + bl;
    float mu  = wave_sum(v) * (1.f / 64.f);
    float df  = v - mu;
    float var = wave_sum(df * df) * (1.f / 64.f);
    float rs  = rsqrtf(var + 1e-5f);
    float o   = df * rs * gl + bt;
    o = o >= 0.f ? o : pw * o;
    out[(size_t)d * CDIM + lane] = o;
}

extern "C" void kernel_launch(void* const* d_in, const int* in_sizes, int n_in,
                              void* d_out, int out_size, void* d_ws, size_t ws_size,
                              hipStream_t stream)
{
    const float* x       = (const float*)d_in[0];
    const int*   ei      = (const int*)  d_in[1];
    const float* W       = (const float*)d_in[2];
    const float* att_src = (const float*)d_in[3];
    const float* att_dst = (const float*)d_in[4];
    const float* bias    = (const float*)d_in[5];
    const float* gamma   = (const float*)d_in[6];
    const float* beta    = (const float*)d_in[7];
    const float* prelu   = (const float*)d_in[8];

    const int N = in_sizes[0] / INDIM;
    const int E = in_sizes[1] / 2;
    float* out = (float*)d_out;

    const int NBUK = (N + 255) >> 8;            // buckets of 256 nodes
    const int EPB  = (E + NPB - 1) / NPB;       // edges per partition block
    const int NCNT = NBUK * NPB;                // counts length

    // workspace layout
    uint2*    hp     = (uint2*)d_ws;                      // N*64 uint2 (25.6 MB)
    float*    a_src  = (float*)(hp + (size_t)N * CDIM);   // N*4 f
    float*    a_dst  = a_src + (size_t)N * HEADS;         // N*4 f
    int*      deg    = (int*)(a_dst + (size_t)N * HEADS); // N
    int*      off    = deg + N;                           // N
    int*      counts = off + N;                           // NBUK*256
    int*      bsum   = counts + NCNT;                     // <=1024
    unsigned* srt    = (unsigned*)(bsum + 1024);          // E u32 (packed)
    int*      csr    = (int*)(srt + E);                   // E
    unsigned short* Waug = (unsigned short*)(csr + E);    // 272*128 bf16

    k_count_prep<<<NPB, 256, 0, stream>>>(ei, E, EPB, NBUK, counts,
                                          W, att_src, att_dst, Waug);
    k_scan1<<<NBUK, 256, 0, stream>>>(counts, bsum, NCNT);
    k_scanip2<<<NBUK, 256, 0, stream>>>(counts, bsum, NBUK, NCNT);
    k_part<<<NPB, 256, 0, stream>>>(ei, E, EPB, NBUK, counts, srt);
    k_bcsr<<<NBUK, 256, 0, stream>>>(srt, counts, E, N, NBUK, deg, off, csr);

    gemm_mfma<<<(N + 127) / 128, 512, 69632, stream>>>(
        x, Waug, hp, a_src, a_dst, N);

    aggr_fused<<<(N + 3) / 4, 256, 0, stream>>>(
        off, deg, csr, (const float4*)a_src, (const float4*)a_dst, hp,
        bias, gamma, beta, prelu, out, N);
}